// Round 1
// baseline (109.568 us; speedup 1.0000x reference)
//
#include <hip/hip_runtime.h>

#define B_      2
#define C_      256
#define H_      96
#define W_      96
#define P_      7
#define NROIS_  512
#define SCALE_  0.0625f
#define TSTD_   0.1f

// ---------------------------------------------------------------------------
// Pass 1: transpose feat (B,C,H*W) -> (B,H*W,C) so channel gathers coalesce.
// ---------------------------------------------------------------------------
__global__ __launch_bounds__(256) void nchw_to_nhwc(const float* __restrict__ in,
                                                    float* __restrict__ out) {
    __shared__ float tile[32][33];          // +1 pad: conflict-free transpose
    const int b  = blockIdx.z;
    const int p0 = blockIdx.x * 32;         // position (h*W+w) tile origin
    const int c0 = blockIdx.y * 32;         // channel tile origin
    const int tx = threadIdx.x;             // 0..31
    const int ty = threadIdx.y;             // 0..7
    const float* src = in  + (size_t)b * (C_ * H_ * W_);
    float*       dst = out + (size_t)b * (C_ * H_ * W_);
#pragma unroll
    for (int k = 0; k < 32; k += 8)
        tile[ty + k][tx] = src[(size_t)(c0 + ty + k) * (H_ * W_) + p0 + tx];
    __syncthreads();
#pragma unroll
    for (int k = 0; k < 32; k += 8)
        dst[(size_t)(p0 + ty + k) * C_ + c0 + tx] = tile[tx][ty + k];
}

// ---------------------------------------------------------------------------
// Pass 2: one block per roi. Wave w handles bins w, w+4, ... (geometry is
// wave-uniform). Lane l owns channels 4l..4l+3 (float4 gathers from HWC feat).
// Results staged in LDS in the exact global layout, then written coalesced.
// ---------------------------------------------------------------------------
template <bool HWC>
__global__ __launch_bounds__(256) void dpsroi_pool(const float* __restrict__ feat,
                                                   const float* __restrict__ rois,
                                                   const float* __restrict__ trans,
                                                   float* __restrict__ out) {
    __shared__ float sout[C_ * P_ * P_];    // 256*49 floats = 50176 B

    const int n    = blockIdx.x;
    const int tid  = threadIdx.x;
    const int wave = tid >> 6;
    const int lane = tid & 63;

    // ROI geometry (uniform across block)
    const float r0  = rois[n * 5 + 0];
    const float rx1 = rois[n * 5 + 1];
    const float ry1 = rois[n * 5 + 2];
    const float rx2 = rois[n * 5 + 3];
    const float ry2 = rois[n * 5 + 4];
    const int   broi = (int)r0;
    const float x1 = rintf(rx1) * SCALE_ - 0.5f;
    const float y1 = rintf(ry1) * SCALE_ - 0.5f;
    const float x2 = (rintf(rx2) + 1.0f) * SCALE_ - 0.5f;
    const float y2 = (rintf(ry2) + 1.0f) * SCALE_ - 0.5f;
    const float rw = fmaxf(x2 - x1, 0.1f);
    const float rh = fmaxf(y2 - y1, 0.1f);
    const float bin_w = rw / 7.0f;
    const float bin_h = rh / 7.0f;
    const float sub_w = bin_w * 0.5f;
    const float sub_h = bin_h * 0.5f;

    for (int bin = wave; bin < P_ * P_; bin += 4) {
        const int pi = bin / P_;            // h (row) pooled index
        const int pj = bin % P_;            // w (col) pooled index

        const float tx = trans[((n * 2 + 0) * P_ + pi) * P_ + pj] * TSTD_;
        const float ty = trans[((n * 2 + 1) * P_ + pi) * P_ + pj] * TSTD_;
        const float wstart = (float)pj * bin_w + x1 + tx * rw;
        const float hstart = (float)pi * bin_h + y1 + ty * rh;

        float acc0 = 0.f, acc1 = 0.f, acc2 = 0.f, acc3 = 0.f;
        int cnt = 0;
#pragma unroll
        for (int sa = 0; sa < 2; ++sa) {
#pragma unroll
            for (int sb = 0; sb < 2; ++sb) {
                const float w = wstart + (float)sb * sub_w;
                const float h = hstart + (float)sa * sub_h;
                // validity on UNclipped coords (wave-uniform branch)
                if (w >= -0.5f && w <= (float)W_ - 0.5f &&
                    h >= -0.5f && h <= (float)H_ - 0.5f) {
                    ++cnt;
                    const float wc  = fminf(fmaxf(w, 0.0f), (float)(W_ - 1));
                    const float hc  = fminf(fmaxf(h, 0.0f), (float)(H_ - 1));
                    const float x0f = floorf(wc), y0f = floorf(hc);
                    const float dx  = wc - x0f,   dy  = hc - y0f;
                    const int   x0  = (int)x0f,   y0  = (int)y0f;
                    const int   xp  = (int)ceilf(wc), yp = (int)ceilf(hc);
                    const float w00 = (1.0f - dx) * (1.0f - dy);
                    const float w01 = dx * (1.0f - dy);
                    const float w10 = (1.0f - dx) * dy;
                    const float w11 = dx * dy;

                    if (HWC) {
                        const float* fb = feat + (size_t)broi * (H_ * W_ * C_);
                        const float4* p00 = (const float4*)(fb + ((size_t)y0 * W_ + x0) * C_) + lane;
                        const float4* p01 = (const float4*)(fb + ((size_t)y0 * W_ + xp) * C_) + lane;
                        const float4* p10 = (const float4*)(fb + ((size_t)yp * W_ + x0) * C_) + lane;
                        const float4* p11 = (const float4*)(fb + ((size_t)yp * W_ + xp) * C_) + lane;
                        const float4 v00 = *p00;
                        const float4 v01 = *p01;
                        const float4 v10 = *p10;
                        const float4 v11 = *p11;
                        acc0 += w00 * v00.x + w01 * v01.x + w10 * v10.x + w11 * v11.x;
                        acc1 += w00 * v00.y + w01 * v01.y + w10 * v10.y + w11 * v11.y;
                        acc2 += w00 * v00.z + w01 * v01.z + w10 * v10.z + w11 * v11.z;
                        acc3 += w00 * v00.w + w01 * v01.w + w10 * v10.w + w11 * v11.w;
                    } else {
                        // CHW fallback (only if workspace too small for transpose)
                        float a[4];
#pragma unroll
                        for (int k = 0; k < 4; ++k) {
                            const int c = 4 * lane + k;
                            const float* fc = feat + (((size_t)broi * C_ + c) * H_) * W_;
                            const float v00 = fc[(size_t)y0 * W_ + x0];
                            const float v01 = fc[(size_t)y0 * W_ + xp];
                            const float v10 = fc[(size_t)yp * W_ + x0];
                            const float v11 = fc[(size_t)yp * W_ + xp];
                            a[k] = w00 * v00 + w01 * v01 + w10 * v10 + w11 * v11;
                        }
                        acc0 += a[0]; acc1 += a[1]; acc2 += a[2]; acc3 += a[3];
                    }
                }
            }
        }

        const float inv = (cnt > 0) ? (1.0f / (float)cnt) : 0.0f;
        const int c4 = 4 * lane;
        sout[(c4 + 0) * (P_ * P_) + bin] = acc0 * inv;
        sout[(c4 + 1) * (P_ * P_) + bin] = acc1 * inv;
        sout[(c4 + 2) * (P_ * P_) + bin] = acc2 * inv;
        sout[(c4 + 3) * (P_ * P_) + bin] = acc3 * inv;
    }

    __syncthreads();
    float* outn = out + (size_t)n * (C_ * P_ * P_);
    for (int f = tid; f < C_ * P_ * P_; f += 256)
        outn[f] = sout[f];   // fully coalesced; LDS read is 2-way (free)
}

extern "C" void kernel_launch(void* const* d_in, const int* in_sizes, int n_in,
                              void* d_out, int out_size, void* d_ws, size_t ws_size,
                              hipStream_t stream) {
    const float* feat  = (const float*)d_in[0];   // (2,256,96,96)
    const float* rois  = (const float*)d_in[1];   // (512,5)
    const float* trans = (const float*)d_in[2];   // (512,2,7,7)
    float* out = (float*)d_out;                   // (512,256,7,7)

    const size_t need = (size_t)B_ * C_ * H_ * W_ * sizeof(float);
    if (ws_size >= need) {
        float* hwc = (float*)d_ws;
        dim3 tb(32, 8);
        dim3 tg((H_ * W_) / 32, C_ / 32, B_);
        nchw_to_nhwc<<<tg, tb, 0, stream>>>(feat, hwc);
        dpsroi_pool<true><<<NROIS_, 256, 0, stream>>>(hwc, rois, trans, out);
    } else {
        dpsroi_pool<false><<<NROIS_, 256, 0, stream>>>(feat, rois, trans, out);
    }
}

// Round 2
// 98.157 us; speedup vs baseline: 1.1163x; 1.1163x over previous
//
#include <hip/hip_runtime.h>

#define B_      2
#define C_      256
#define H_      96
#define W_      96
#define P_      7
#define NROIS_  512
#define SCALE_  0.0625f
#define TSTD_   0.1f

#define NGROUP_ 8                       // channel groups (one per XCD)
#define GC_     (C_ / NGROUP_)          // 32 channels per group

// ---------------------------------------------------------------------------
// Pass 1: transpose feat (B,C,H*W) -> (B,H*W,C) so channel gathers coalesce.
// ---------------------------------------------------------------------------
__global__ __launch_bounds__(256) void nchw_to_nhwc(const float* __restrict__ in,
                                                    float* __restrict__ out) {
    __shared__ float tile[32][33];          // +1 pad: conflict-free transpose
    const int b  = blockIdx.z;
    const int p0 = blockIdx.x * 32;         // position (h*W+w) tile origin
    const int c0 = blockIdx.y * 32;         // channel tile origin
    const int tx = threadIdx.x;             // 0..31
    const int ty = threadIdx.y;             // 0..7
    const float* src = in  + (size_t)b * (C_ * H_ * W_);
    float*       dst = out + (size_t)b * (C_ * H_ * W_);
#pragma unroll
    for (int k = 0; k < 32; k += 8)
        tile[ty + k][tx] = src[(size_t)(c0 + ty + k) * (H_ * W_) + p0 + tx];
    __syncthreads();
#pragma unroll
    for (int k = 0; k < 32; k += 8)
        dst[(size_t)(p0 + ty + k) * C_ + c0 + tx] = tile[tx][ty + k];
}

// ---------------------------------------------------------------------------
// Pass 2: block = (roi n, channel-group g). g = blockIdx.x & 7 so round-robin
// block->XCD dispatch pins each 32-channel slice (2.36 MB working set) to one
// XCD's 4 MB L2 -> all gathers L2-resident. 8 lanes/bin x float4 = 32 ch,
// 128 B contiguous + aligned per corner read. LDS 6.3 KB -> 32 waves/CU.
// ---------------------------------------------------------------------------
__global__ __launch_bounds__(256) void dpsroi_pool2(const float* __restrict__ feat,  // HWC
                                                    const float* __restrict__ rois,
                                                    const float* __restrict__ trans,
                                                    float* __restrict__ out) {
    __shared__ float sout[GC_ * P_ * P_];   // 32*49*4 = 6272 B, global layout

    const int blk = blockIdx.x;
    const int g   = blk & (NGROUP_ - 1);    // channel group -> XCD affinity
    const int n   = blk >> 3;               // roi
    const int tid = threadIdx.x;
    const int cl  = (tid & 7) * 4;          // channel-in-group: 0,4,...,28
    const int cab = g * GC_ + cl;           // absolute channel offset in HWC

    // ROI geometry (block-uniform)
    const int   broi = (int)rois[n * 5 + 0];
    const float x1 = rintf(rois[n * 5 + 1]) * SCALE_ - 0.5f;
    const float y1 = rintf(rois[n * 5 + 2]) * SCALE_ - 0.5f;
    const float x2 = (rintf(rois[n * 5 + 3]) + 1.0f) * SCALE_ - 0.5f;
    const float y2 = (rintf(rois[n * 5 + 4]) + 1.0f) * SCALE_ - 0.5f;
    const float rw = fmaxf(x2 - x1, 0.1f);
    const float rh = fmaxf(y2 - y1, 0.1f);
    const float bin_w = rw * (1.0f / 7.0f);
    const float bin_h = rh * (1.0f / 7.0f);
    const float sub_w = bin_w * 0.5f;
    const float sub_h = bin_h * 0.5f;

    const float* fb = feat + (size_t)broi * (H_ * W_ * C_) + cab;

    // 256 threads = 8 lanes/bin x 32 bins per sweep; 49 bins -> 2 sweeps.
    for (int bin = tid >> 3; bin < P_ * P_; bin += 32) {
        const int pi = bin / P_;
        const int pj = bin - pi * P_;

        const float tx = trans[((n * 2 + 0) * P_ + pi) * P_ + pj] * TSTD_;
        const float ty = trans[((n * 2 + 1) * P_ + pi) * P_ + pj] * TSTD_;
        const float wstart = (float)pj * bin_w + x1 + tx * rw;
        const float hstart = (float)pi * bin_h + y1 + ty * rh;

        float acc0 = 0.f, acc1 = 0.f, acc2 = 0.f, acc3 = 0.f;
        int cnt = 0;
#pragma unroll
        for (int sa = 0; sa < 2; ++sa) {
#pragma unroll
            for (int sb = 0; sb < 2; ++sb) {
                const float w = wstart + (float)sb * sub_w;
                const float h = hstart + (float)sa * sub_h;
                if (w >= -0.5f && w <= (float)W_ - 0.5f &&
                    h >= -0.5f && h <= (float)H_ - 0.5f) {
                    ++cnt;
                    const float wc  = fminf(fmaxf(w, 0.0f), (float)(W_ - 1));
                    const float hc  = fminf(fmaxf(h, 0.0f), (float)(H_ - 1));
                    const float x0f = floorf(wc), y0f = floorf(hc);
                    const float dx  = wc - x0f,   dy  = hc - y0f;
                    const int   x0  = (int)x0f,   y0  = (int)y0f;
                    const int   xp  = (int)ceilf(wc), yp = (int)ceilf(hc);
                    const float w00 = (1.0f - dx) * (1.0f - dy);
                    const float w01 = dx * (1.0f - dy);
                    const float w10 = (1.0f - dx) * dy;
                    const float w11 = dx * dy;

                    const float4 v00 = *(const float4*)(fb + ((size_t)y0 * W_ + x0) * C_);
                    const float4 v01 = *(const float4*)(fb + ((size_t)y0 * W_ + xp) * C_);
                    const float4 v10 = *(const float4*)(fb + ((size_t)yp * W_ + x0) * C_);
                    const float4 v11 = *(const float4*)(fb + ((size_t)yp * W_ + xp) * C_);
                    acc0 += w00 * v00.x + w01 * v01.x + w10 * v10.x + w11 * v11.x;
                    acc1 += w00 * v00.y + w01 * v01.y + w10 * v10.y + w11 * v11.y;
                    acc2 += w00 * v00.z + w01 * v01.z + w10 * v10.z + w11 * v11.z;
                    acc3 += w00 * v00.w + w01 * v01.w + w10 * v10.w + w11 * v11.w;
                }
            }
        }

        const float inv = (cnt > 0) ? (1.0f / (float)cnt) : 0.0f;
        sout[(cl + 0) * (P_ * P_) + bin] = acc0 * inv;
        sout[(cl + 1) * (P_ * P_) + bin] = acc1 * inv;
        sout[(cl + 2) * (P_ * P_) + bin] = acc2 * inv;
        sout[(cl + 3) * (P_ * P_) + bin] = acc3 * inv;
    }

    __syncthreads();
    // out[n, g*32 : g*32+32, :, :] is contiguous: 32*49 floats
    float* outn = out + ((size_t)n * C_ + g * GC_) * (P_ * P_);
    for (int f = tid; f < GC_ * P_ * P_; f += 256)
        outn[f] = sout[f];
}

extern "C" void kernel_launch(void* const* d_in, const int* in_sizes, int n_in,
                              void* d_out, int out_size, void* d_ws, size_t ws_size,
                              hipStream_t stream) {
    const float* feat  = (const float*)d_in[0];   // (2,256,96,96)
    const float* rois  = (const float*)d_in[1];   // (512,5)
    const float* trans = (const float*)d_in[2];   // (512,2,7,7)
    float* out = (float*)d_out;                   // (512,256,7,7)

    float* hwc = (float*)d_ws;                    // 18.9 MB; ws is 256 MiB
    dim3 tb(32, 8);
    dim3 tg((H_ * W_) / 32, C_ / 32, B_);
    nchw_to_nhwc<<<tg, tb, 0, stream>>>(feat, hwc);
    dpsroi_pool2<<<NROIS_ * NGROUP_, 256, 0, stream>>>(hwc, rois, trans, out);
}